// Round 1
// baseline (10551.546 us; speedup 1.0000x reference)
//
#include <hip/hip_runtime.h>
#include <math.h>

// RepCodec: Vocos encoder (fp32 vector GEMMs) + factorized VQ.
// B=8, T=2048 -> M=16384 tokens; H=1024, D=384, I=2048, L=12, CB=8192, CD=8.

#define BMG 128
#define BNG 128
#define BKG 16

__device__ __forceinline__ float gelu_exact(float x){
  return 0.5f * x * (1.0f + erff(x * 0.70710678118654752f));
}

// ---------------- prep kernels ----------------

// embed weight (D,H,7) -> wkT (7,D,H) so each tap is an NT-GEMM weight (N=384,K=1024) row-major
__global__ __launch_bounds__(256) void prep_wk(const float* __restrict__ w, float* __restrict__ wkT){
  int i = blockIdx.x*256 + threadIdx.x;
  if (i >= 384*1024) return;
  int d = i >> 10, c = i & 1023;
  #pragma unroll
  for (int k=0;k<7;k++)
    wkT[(size_t)k*(384*1024) + (size_t)d*1024 + c] = w[(size_t)d*(1024*7) + (size_t)c*7 + k];
}

// codebook (8192,8) -> L2-normalized copy
__global__ __launch_bounds__(256) void prep_cb(const float* __restrict__ cb, float* __restrict__ cbn){
  int e = blockIdx.x*256 + threadIdx.x;
  if (e >= 8192) return;
  float v[8], s = 0.f;
  #pragma unroll
  for (int cd=0; cd<8; ++cd){ v[cd] = cb[(size_t)e*8+cd]; s += v[cd]*v[cd]; }
  float inv = 1.0f / fmaxf(sqrtf(s), 1e-12f);
  #pragma unroll
  for (int cd=0; cd<8; ++cd) cbn[(size_t)e*8+cd] = v[cd]*inv;
}

// ---------------- GEMM core ----------------

__device__ __forceinline__ void stage8(float dst[BKG][BMG], int lcol, int lrow, float4 a0, float4 a1){
  dst[lcol+0][lrow]=a0.x; dst[lcol+1][lrow]=a0.y; dst[lcol+2][lrow]=a0.z; dst[lcol+3][lrow]=a0.w;
  dst[lcol+4][lrow]=a1.x; dst[lcol+5][lrow]=a1.y; dst[lcol+6][lrow]=a1.z; dst[lcol+7][lrow]=a1.w;
}

__device__ __forceinline__ void mma_step(const float As[BKG][BMG], const float Bs[BKG][BNG],
                                         int tx, int ty, float acc[8][8]){
  #pragma unroll
  for (int kk=0; kk<BKG; ++kk){
    float af[8], bf[8];
    *(float4*)&af[0] = *(const float4*)&As[kk][ty*8];
    *(float4*)&af[4] = *(const float4*)&As[kk][ty*8+4];
    *(float4*)&bf[0] = *(const float4*)&Bs[kk][tx*8];
    *(float4*)&bf[4] = *(const float4*)&Bs[kk][tx*8+4];
    #pragma unroll
    for (int i=0;i<8;i++)
      #pragma unroll
      for (int j=0;j<8;j++)
        acc[i][j] = fmaf(af[i], bf[j], acc[i][j]);
  }
}

// C = epilogue(A @ W^T). A:(M,K) lda, W:(N,K) ldw row-major.
// EPI 0: C = acc + bias
// EPI 1: C = gelu(acc + bias)
// EPI 2: C = C + gamma * (acc + (bias ? bias : 0))
template<int EPI>
__global__ __launch_bounds__(256) void gemm_nt(
    const float* __restrict__ A, int lda,
    const float* __restrict__ W, int ldw,
    const float* __restrict__ bias,
    const float* __restrict__ gamma,
    float* __restrict__ C, int ldc, int K)
{
  __shared__ float As[BKG][BMG];
  __shared__ float Bs[BKG][BNG];
  const int tid = threadIdx.x;
  const int m0 = blockIdx.y * BMG;
  const int n0 = blockIdx.x * BNG;
  const int tx = tid & 15, ty = tid >> 4;
  const int lrow = tid >> 1, lcol = (tid & 1) << 3;
  const float* Ap = A + (size_t)(m0+lrow)*lda + lcol;
  const float* Wp = W + (size_t)(n0+lrow)*ldw + lcol;
  float acc[8][8] = {};
  for (int k0=0;k0<K;k0+=BKG){
    float4 a0 = *(const float4*)(Ap + k0);
    float4 a1 = *(const float4*)(Ap + k0 + 4);
    float4 b0 = *(const float4*)(Wp + k0);
    float4 b1 = *(const float4*)(Wp + k0 + 4);
    __syncthreads();
    stage8(As, lcol, lrow, a0, a1);
    stage8(Bs, lcol, lrow, b0, b1);
    __syncthreads();
    mma_step(As, Bs, tx, ty, acc);
  }
  const bool hasb = (bias != nullptr);
  float bj[8], gj[8];
  #pragma unroll
  for (int j=0;j<8;j++) bj[j] = hasb ? bias[n0 + tx*8 + j] : 0.0f;
  if (EPI == 2){
    #pragma unroll
    for (int j=0;j<8;j++) gj[j] = gamma[n0 + tx*8 + j];
  }
  #pragma unroll
  for (int i=0;i<8;i++){
    float* crow = C + (size_t)(m0 + ty*8 + i)*ldc + n0 + tx*8;
    float o[8];
    if (EPI == 2){
      float4 c0 = *(const float4*)&crow[0];
      float4 c1 = *(const float4*)&crow[4];
      o[0]=c0.x; o[1]=c0.y; o[2]=c0.z; o[3]=c0.w; o[4]=c1.x; o[5]=c1.y; o[6]=c1.z; o[7]=c1.w;
      #pragma unroll
      for (int j=0;j<8;j++) o[j] += gj[j]*(acc[i][j] + bj[j]);
    } else {
      #pragma unroll
      for (int j=0;j<8;j++){
        float v = acc[i][j] + bj[j];
        if (EPI == 1) v = gelu_exact(v);
        o[j] = v;
      }
    }
    *(float4*)&crow[0] = make_float4(o[0],o[1],o[2],o[3]);
    *(float4*)&crow[4] = make_float4(o[4],o[5],o[6],o[7]);
  }
}

// embed conv as 7 shifted NT-GEMMs, M=16384, N=384, K=1024 per tap.
__global__ __launch_bounds__(256) void embed_gemm(
    const float* __restrict__ x, const float* __restrict__ wkT,
    const float* __restrict__ bias, float* __restrict__ C)
{
  __shared__ float As[BKG][BMG];
  __shared__ float Bs[BKG][BNG];
  const int tid = threadIdx.x;
  const int m0 = blockIdx.y * BMG;
  const int n0 = blockIdx.x * BNG;
  const int tx = tid & 15, ty = tid >> 4;
  const int lrow = tid >> 1, lcol = (tid & 1) << 3;
  const int gr = m0 + lrow;
  const int tb = gr & 2047;
  const float* Wbase = wkT + (size_t)(n0+lrow)*1024 + lcol;
  float acc[8][8] = {};
  for (int k=0;k<7;k++){
    const int tt = tb + k - 3;
    const bool valid = ((unsigned)tt < 2048u);
    const float* Ap = x + (size_t)(gr + k - 3)*1024 + lcol;
    const float* Wp = Wbase + (size_t)k*(384*1024);
    for (int k0=0;k0<1024;k0+=BKG){
      float4 a0, a1;
      if (valid){ a0 = *(const float4*)(Ap + k0); a1 = *(const float4*)(Ap + k0 + 4); }
      else { a0 = make_float4(0,0,0,0); a1 = a0; }
      float4 b0 = *(const float4*)(Wp + k0);
      float4 b1 = *(const float4*)(Wp + k0 + 4);
      __syncthreads();
      stage8(As, lcol, lrow, a0, a1);
      stage8(Bs, lcol, lrow, b0, b1);
      __syncthreads();
      mma_step(As, Bs, tx, ty, acc);
    }
  }
  float bj[8];
  #pragma unroll
  for (int j=0;j<8;j++) bj[j] = bias[n0 + tx*8 + j];
  #pragma unroll
  for (int i=0;i<8;i++){
    float* crow = C + (size_t)(m0 + ty*8 + i)*384 + n0 + tx*8;
    *(float4*)&crow[0] = make_float4(acc[i][0]+bj[0], acc[i][1]+bj[1], acc[i][2]+bj[2], acc[i][3]+bj[3]);
    *(float4*)&crow[4] = make_float4(acc[i][4]+bj[4], acc[i][5]+bj[5], acc[i][6]+bj[6], acc[i][7]+bj[7]);
  }
}

// ---------------- LN (optionally fused depthwise conv k=7) ----------------
// one row (D=384) per block, 384 threads.
template<bool CONV>
__global__ __launch_bounds__(384) void ln_kernel(
    const float* __restrict__ in,
    const float* __restrict__ dw, const float* __restrict__ db,
    const float* __restrict__ g, const float* __restrict__ b,
    float* __restrict__ out)
{
  __shared__ float rs[6], rs2[6], stat[2];
  const int m = blockIdx.x, d = threadIdx.x;
  float v;
  if (CONV){
    const int t = m & 2047;
    float a = db[d];
    #pragma unroll
    for (int k=0;k<7;k++){
      int tt = t + k - 3;
      if ((unsigned)tt < 2048u) a = fmaf(in[(size_t)(m + k - 3)*384 + d], dw[d*7 + k], a);
    }
    v = a;
  } else {
    v = in[(size_t)m*384 + d];
  }
  float s = v, s2 = v*v;
  #pragma unroll
  for (int o=1;o<64;o<<=1){ s += __shfl_xor(s,o); s2 += __shfl_xor(s2,o); }
  const int wid = d >> 6, lane = d & 63;
  if (lane == 0){ rs[wid]=s; rs2[wid]=s2; }
  __syncthreads();
  if (d == 0){
    float S=0.f, S2=0.f;
    #pragma unroll
    for (int w=0;w<6;w++){ S+=rs[w]; S2+=rs2[w]; }
    float mean = S*(1.0f/384.0f);
    float var = fmaxf(S2*(1.0f/384.0f) - mean*mean, 0.0f);
    stat[0]=mean; stat[1]=1.0f/sqrtf(var + 1e-6f);
  }
  __syncthreads();
  out[(size_t)m*384 + d] = (v - stat[0])*stat[1]*g[d] + b[d];
}

// ---------------- VQ ----------------

// z_n: one token per wave; W_in (8,1024) staged in LDS.
__global__ __launch_bounds__(256) void vq_in_kernel(
    const float* __restrict__ enc, const float* __restrict__ wi,
    const float* __restrict__ bi, float* __restrict__ zn)
{
  __shared__ float sw[8192];
  const int tid = threadIdx.x;
  for (int i = tid*4; i < 8192; i += 1024) *(float4*)&sw[i] = *(const float4*)&wi[i];
  __syncthreads();
  const int wid = tid >> 6, lane = tid & 63;
  const size_t m = (size_t)blockIdx.x*4 + wid;
  float acc[8] = {};
  for (int j=0;j<16;j++){
    float v = enc[m*1024 + j*64 + lane];
    #pragma unroll
    for (int cd=0;cd<8;cd++) acc[cd] = fmaf(v, sw[cd*1024 + j*64 + lane], acc[cd]);
  }
  #pragma unroll
  for (int cd=0;cd<8;cd++)
    #pragma unroll
    for (int o=1;o<64;o<<=1) acc[cd] += __shfl_xor(acc[cd], o);
  if (lane == 0){
    float z[8], s = 0.f;
    #pragma unroll
    for (int cd=0;cd<8;cd++){ z[cd] = acc[cd] + bi[cd]; s += z[cd]*z[cd]; }
    float inv = 1.0f / fmaxf(sqrtf(s), 1e-12f);
    #pragma unroll
    for (int cd=0;cd<8;cd++) zn[m*8+cd] = z[cd]*inv;
  }
}

// cosine-sim argmax over 8192 normalized entries; first-max tie-break (ascending, strict >).
__global__ __launch_bounds__(256) void vq_argmax(
    const float* __restrict__ zn, const float* __restrict__ cbn,
    int* __restrict__ idx_out, float* __restrict__ idx_f)
{
  __shared__ float cbs[1024*8];
  const int tid = threadIdx.x;
  const size_t m = (size_t)blockIdx.x*256 + tid;
  float z[8];
  float4 z0 = *(const float4*)&zn[m*8];
  float4 z1 = *(const float4*)&zn[m*8+4];
  z[0]=z0.x; z[1]=z0.y; z[2]=z0.z; z[3]=z0.w; z[4]=z1.x; z[5]=z1.y; z[6]=z1.z; z[7]=z1.w;
  float best = -1e30f; int bidx = 0;
  for (int c0 = 0; c0 < 8192; c0 += 1024){
    __syncthreads();
    for (int i = tid*4; i < 8192; i += 1024) *(float4*)&cbs[i] = *(const float4*)&cbn[(size_t)c0*8 + i];
    __syncthreads();
    #pragma unroll 4
    for (int e = 0; e < 1024; ++e){
      const float4 ca = *(const float4*)&cbs[e*8];
      const float4 cb4 = *(const float4*)&cbs[e*8+4];
      float s = z[0]*ca.x + z[1]*ca.y + z[2]*ca.z + z[3]*ca.w
              + z[4]*cb4.x + z[5]*cb4.y + z[6]*cb4.z + z[7]*cb4.w;
      if (s > best){ best = s; bidx = c0 + e; }
    }
  }
  idx_out[m] = bidx;
  idx_f[m] = (float)bidx;
}

// quantized = codebook[idx] @ vq_out_w^T + b. 16 tokens per block.
__global__ __launch_bounds__(256) void vq_out_kernel(
    const int* __restrict__ idx, const float* __restrict__ cb,
    const float* __restrict__ wo, const float* __restrict__ bo,
    float* __restrict__ outq)
{
  __shared__ float wT[8][1024];
  __shared__ float cbs[16][8];
  __shared__ int idxs[16];
  const int tid = threadIdx.x;
  #pragma unroll
  for (int j=0;j<4;j++){
    int hcol = j*256 + tid;
    float4 w0 = *(const float4*)&wo[(size_t)hcol*8];
    float4 w1 = *(const float4*)&wo[(size_t)hcol*8+4];
    wT[0][hcol]=w0.x; wT[1][hcol]=w0.y; wT[2][hcol]=w0.z; wT[3][hcol]=w0.w;
    wT[4][hcol]=w1.x; wT[5][hcol]=w1.y; wT[6][hcol]=w1.z; wT[7][hcol]=w1.w;
  }
  if (tid < 16) idxs[tid] = idx[blockIdx.x*16 + tid];
  __syncthreads();
  if (tid < 128){ int tk = tid>>3, cd = tid&7; cbs[tk][cd] = cb[(size_t)idxs[tk]*8 + cd]; }
  __syncthreads();
  float bb[4];
  #pragma unroll
  for (int j=0;j<4;j++) bb[j] = bo[j*256+tid];
  for (int tk=0;tk<16;tk++){
    const size_t m = (size_t)blockIdx.x*16 + tk;
    float c0=cbs[tk][0], c1=cbs[tk][1], c2=cbs[tk][2], c3=cbs[tk][3];
    float c4=cbs[tk][4], c5=cbs[tk][5], c6=cbs[tk][6], c7=cbs[tk][7];
    #pragma unroll
    for (int j=0;j<4;j++){
      int hcol = j*256 + tid;
      float v = bb[j];
      v = fmaf(c0, wT[0][hcol], v); v = fmaf(c1, wT[1][hcol], v);
      v = fmaf(c2, wT[2][hcol], v); v = fmaf(c3, wT[3][hcol], v);
      v = fmaf(c4, wT[4][hcol], v); v = fmaf(c5, wT[5][hcol], v);
      v = fmaf(c6, wT[6][hcol], v); v = fmaf(c7, wT[7][hcol], v);
      outq[m*1024 + hcol] = v;
    }
  }
}

// ---------------- host ----------------

extern "C" void kernel_launch(void* const* d_in, const int* in_sizes, int n_in,
                              void* d_out, int out_size, void* d_ws, size_t ws_size,
                              hipStream_t stream) {
  (void)in_sizes; (void)n_in; (void)out_size; (void)ws_size;
  const float* x   = (const float*)d_in[0];
  const float* eww = (const float*)d_in[1];
  const float* ewb = (const float*)d_in[2];
  const float* ng  = (const float*)d_in[3];
  const float* nb  = (const float*)d_in[4];
  const float* dww = (const float*)d_in[5];
  const float* dwb = (const float*)d_in[6];
  const float* lng = (const float*)d_in[7];
  const float* lnb = (const float*)d_in[8];
  const float* w1  = (const float*)d_in[9];
  const float* b1  = (const float*)d_in[10];
  const float* w2  = (const float*)d_in[11];
  const float* b2  = (const float*)d_in[12];
  const float* gma = (const float*)d_in[13];
  const float* fg  = (const float*)d_in[14];
  const float* fb  = (const float*)d_in[15];
  const float* ow  = (const float*)d_in[16];
  const float* ob  = (const float*)d_in[17];
  const float* viw = (const float*)d_in[18];
  const float* vib = (const float*)d_in[19];
  const float* cb  = (const float*)d_in[20];
  const float* vow = (const float*)d_in[21];
  const float* vob = (const float*)d_in[22];
  float* out = (float*)d_out;

  // workspace layout (floats); total ~123.3 MiB
  float* ws  = (float*)d_ws;
  float* wkT = ws;                      // 7*384*1024        = 2,752,512
  float* h   = wkT + 2752512;           // 16384*384         = 6,291,456
  float* y   = h   + 6291456;           // 16384*384
  float* y1  = y   + 6291456;           // 16384*1024        = 16,777,216 (I-chunk buf, later enc)
  float* zn  = y1  + 16777216;          // 16384*8           = 131,072
  float* cbn = zn  + 131072;            // 8192*8            = 65,536
  int*  idxb = (int*)(cbn + 65536);     // 16384 ints

  prep_wk<<<dim3(1536), dim3(256), 0, stream>>>(eww, wkT);
  prep_cb<<<dim3(32),  dim3(256), 0, stream>>>(cb, cbn);

  // embed conv -> y ; LN -> h
  embed_gemm<<<dim3(3,128), dim3(256), 0, stream>>>(x, wkT, ewb, y);
  ln_kernel<false><<<dim3(16384), dim3(384), 0, stream>>>(y, nullptr, nullptr, ng, nb, h);

  // 12 ConvNeXt blocks
  for (int i = 0; i < 12; ++i){
    ln_kernel<true><<<dim3(16384), dim3(384), 0, stream>>>(
        h, dww + (size_t)i*2688, dwb + (size_t)i*384,
        lng + (size_t)i*384, lnb + (size_t)i*384, y);
    for (int ic = 0; ic < 2; ++ic){
      // y1 = gelu(y @ w1_chunk^T + b1_chunk), N=1024, K=384
      gemm_nt<1><<<dim3(8,128), dim3(256), 0, stream>>>(
          y, 384,
          w1 + (size_t)i*2048*384 + (size_t)ic*1024*384, 384,
          b1 + (size_t)i*2048 + (size_t)ic*1024, nullptr,
          y1, 1024, 384);
      // h += gamma * (y1 @ w2_chunk^T + b2(once)), N=384, K=1024
      gemm_nt<2><<<dim3(3,128), dim3(256), 0, stream>>>(
          y1, 1024,
          w2 + (size_t)i*384*2048 + (size_t)ic*1024, 2048,
          (ic == 0) ? (b2 + (size_t)i*384) : nullptr,
          gma + (size_t)i*384,
          h, 384, 1024);
    }
  }

  // final LN -> y ; enc = y @ ow^T + ob  (enc reuses y1 buffer)
  ln_kernel<false><<<dim3(16384), dim3(384), 0, stream>>>(h, nullptr, nullptr, fg, fb, y);
  gemm_nt<0><<<dim3(8,128), dim3(256), 0, stream>>>(y, 384, ow, 384, ob, nullptr, y1, 1024, 384);

  // VQ: z_n, argmax (writes idx as float to out[0:16384]), out-proj to out[16384:]
  vq_in_kernel<<<dim3(4096), dim3(256), 0, stream>>>(y1, viw, vib, zn);
  vq_argmax<<<dim3(64), dim3(256), 0, stream>>>(zn, cbn, idxb, out);
  vq_out_kernel<<<dim3(1024), dim3(256), 0, stream>>>(idxb, cb, vow, vob, out + 16384);
}

// Round 2
// 4475.169 us; speedup vs baseline: 2.3578x; 2.3578x over previous
//
#include <hip/hip_runtime.h>
#include <math.h>

// RepCodec: Vocos encoder + factorized VQ.
// GEMMs on MFMA via fp16 two-term split (hi+lo), 3 passes: hh + hl + lh.
// B=8, T=2048 -> M=16384 tokens; H=1024, D=384, I=2048 (chunked 2x1024), L=12.

typedef _Float16 h8_t __attribute__((ext_vector_type(8)));
typedef float f4_t __attribute__((ext_vector_type(4)));

__device__ __forceinline__ float gelu_exact(float x){
  return 0.5f * x * (1.0f + erff(x * 0.70710678118654752f));
}

__device__ __forceinline__ void split8(const float4& a, const float4& b, h8_t& hi, h8_t& lo){
  float f[8] = {a.x,a.y,a.z,a.w,b.x,b.y,b.z,b.w};
  #pragma unroll
  for (int t=0;t<8;t++){
    _Float16 hh = (_Float16)f[t];
    hi[t] = hh;
    lo[t] = (_Float16)(f[t] - (float)hh);
  }
}

// ---------------- prep kernels ----------------

// embed weight (D,H,7) -> wkT (7,D,H): per-tap NT-GEMM weight (N=384,K=1024) row-major
__global__ __launch_bounds__(256) void prep_wk(const float* __restrict__ w, float* __restrict__ wkT){
  int i = blockIdx.x*256 + threadIdx.x;
  if (i >= 384*1024) return;
  int d = i >> 10, c = i & 1023;
  #pragma unroll
  for (int k=0;k<7;k++)
    wkT[(size_t)k*(384*1024) + (size_t)d*1024 + c] = w[(size_t)d*(1024*7) + (size_t)c*7 + k];
}

// codebook (8192,8) -> L2-normalized copy
__global__ __launch_bounds__(256) void prep_cb(const float* __restrict__ cb, float* __restrict__ cbn){
  int e = blockIdx.x*256 + threadIdx.x;
  if (e >= 8192) return;
  float v[8], s = 0.f;
  #pragma unroll
  for (int cd=0; cd<8; ++cd){ v[cd] = cb[(size_t)e*8+cd]; s += v[cd]*v[cd]; }
  float inv = 1.0f / fmaxf(sqrtf(s), 1e-12f);
  #pragma unroll
  for (int cd=0; cd<8; ++cd) cbn[(size_t)e*8+cd] = v[cd]*inv;
}

// ---------------- MFMA tile core ----------------
// LDS tiles: 128 rows x 32 K halves, hi & lo. Frag read: row=(l&15)+16m(+wave), k=(l>>4)*8.
// All 64 lanes of a wave read distinct 16B chunks covering a contiguous 1KB -> conflict-free.

__device__ __forceinline__ void mma_block(const _Float16* AsH, const _Float16* AsL,
                                          const _Float16* BsH, const _Float16* BsL,
                                          int aoff, int boff, f4_t acc[4][4]){
  h8_t ah[4], al[4], bh[4], bl[4];
  #pragma unroll
  for (int m=0;m<4;m++){
    ah[m] = *(const h8_t*)(AsH + aoff + m*512);
    al[m] = *(const h8_t*)(AsL + aoff + m*512);
  }
  #pragma unroll
  for (int n=0;n<4;n++){
    bh[n] = *(const h8_t*)(BsH + boff + n*512);
    bl[n] = *(const h8_t*)(BsL + boff + n*512);
  }
  #pragma unroll
  for (int m=0;m<4;m++)
    #pragma unroll
    for (int n=0;n<4;n++){
      acc[m][n] = __builtin_amdgcn_mfma_f32_16x16x32_f16(al[m], bh[n], acc[m][n], 0,0,0);
      acc[m][n] = __builtin_amdgcn_mfma_f32_16x16x32_f16(ah[m], bl[n], acc[m][n], 0,0,0);
      acc[m][n] = __builtin_amdgcn_mfma_f32_16x16x32_f16(ah[m], bh[n], acc[m][n], 0,0,0);
    }
}

// C = epilogue(A @ W^T). A: pre-split halves (M,K). W: fp32 (N,K), split on the fly.
// EPI 0: C(fp32) = acc + bias
// EPI 1: Ch/Cl(half splits) = gelu(acc + bias)
// EPI 2: C(fp32) += gamma * (acc + bias?)
template<int EPI>
__global__ __launch_bounds__(256,2) void gemm_f16(
    const _Float16* __restrict__ Ah, const _Float16* __restrict__ Al, int lda,
    const float* __restrict__ W, int ldw,
    const float* __restrict__ bias, const float* __restrict__ gamma,
    float* __restrict__ C, _Float16* __restrict__ Ch, _Float16* __restrict__ Cl,
    int ldc, int K)
{
  __shared__ _Float16 AsH[4096], AsL[4096], BsH[4096], BsL[4096];
  const int tid = threadIdx.x;
  const int m0 = blockIdx.y*128, n0 = blockIdx.x*128;
  const int srow = tid>>2, koff = (tid&3)*8;
  const _Float16* pAh  = Ah + (size_t)(m0+srow)*lda + koff;
  const _Float16* pAl  = Al + (size_t)(m0+srow)*lda + koff;
  const _Float16* pAh1 = pAh + (size_t)64*lda;
  const _Float16* pAl1 = pAl + (size_t)64*lda;
  const float* pB  = W + (size_t)(n0+srow)*ldw + koff;
  const float* pB1 = pB + (size_t)64*ldw;
  const int lane = tid & 63, wid = tid >> 6;
  const int wm = (wid>>1)*64, wn = (wid&1)*64;
  const int fr = lane & 15, kg = lane >> 4;
  const int aoff = (wm+fr)*32 + kg*8;
  const int boff = (wn+fr)*32 + kg*8;
  f4_t acc[4][4] = {};
  for (int k0 = 0; k0 < K; k0 += 32){
    h8_t avh0 = *(const h8_t*)(pAh  + k0);
    h8_t avl0 = *(const h8_t*)(pAl  + k0);
    h8_t avh1 = *(const h8_t*)(pAh1 + k0);
    h8_t avl1 = *(const h8_t*)(pAl1 + k0);
    float4 b0a = *(const float4*)(pB  + k0);
    float4 b0b = *(const float4*)(pB  + k0 + 4);
    float4 b1a = *(const float4*)(pB1 + k0);
    float4 b1b = *(const float4*)(pB1 + k0 + 4);
    __syncthreads();
    *(h8_t*)(AsH + tid*8) = avh0;
    *(h8_t*)(AsL + tid*8) = avl0;
    *(h8_t*)(AsH + 2048 + tid*8) = avh1;
    *(h8_t*)(AsL + 2048 + tid*8) = avl1;
    h8_t hi, lo;
    split8(b0a, b0b, hi, lo);
    *(h8_t*)(BsH + tid*8) = hi; *(h8_t*)(BsL + tid*8) = lo;
    split8(b1a, b1b, hi, lo);
    *(h8_t*)(BsH + 2048 + tid*8) = hi; *(h8_t*)(BsL + 2048 + tid*8) = lo;
    __syncthreads();
    mma_block(AsH, AsL, BsH, BsL, aoff, boff, acc);
  }
  float bj[4], gj[4];
  #pragma unroll
  for (int n=0;n<4;n++){
    int col = n0 + wn + n*16 + fr;
    bj[n] = bias ? bias[col] : 0.0f;
    gj[n] = (EPI==2) ? gamma[col] : 0.0f;
  }
  #pragma unroll
  for (int m=0;m<4;m++){
    #pragma unroll
    for (int r=0;r<4;r++){
      const int row = m0 + wm + m*16 + kg*4 + r;
      #pragma unroll
      for (int n=0;n<4;n++){
        const int col = n0 + wn + n*16 + fr;
        float v = acc[m][n][r] + bj[n];
        if (EPI==0){
          C[(size_t)row*ldc + col] = v;
        } else if (EPI==1){
          v = gelu_exact(v);
          _Float16 hh = (_Float16)v;
          Ch[(size_t)row*ldc + col] = hh;
          Cl[(size_t)row*ldc + col] = (_Float16)(v - (float)hh);
        } else {
          C[(size_t)row*ldc + col] += gj[n]*v;
        }
      }
    }
  }
}

// embed conv as 7 shifted NT-GEMMs on MFMA; A = x fp32 (split on the fly, masked rows).
__global__ __launch_bounds__(256,2) void embed_f16(
    const float* __restrict__ x, const float* __restrict__ wkT,
    const float* __restrict__ bias, float* __restrict__ C)
{
  __shared__ _Float16 AsH[4096], AsL[4096], BsH[4096], BsL[4096];
  const int tid = threadIdx.x;
  const int m0 = blockIdx.y*128, n0 = blockIdx.x*128;
  const int srow = tid>>2, koff = (tid&3)*8;
  const int lane = tid & 63, wid = tid >> 6;
  const int wm = (wid>>1)*64, wn = (wid&1)*64;
  const int fr = lane & 15, kg = lane >> 4;
  const int aoff = (wm+fr)*32 + kg*8;
  const int boff = (wn+fr)*32 + kg*8;
  const int r0 = m0 + srow, r1 = r0 + 64;
  const int t0 = r0 & 2047, t1 = r1 & 2047;
  f4_t acc[4][4] = {};
  for (int k=0;k<7;k++){
    const bool v0 = (unsigned)(t0 + k - 3) < 2048u;
    const bool v1 = (unsigned)(t1 + k - 3) < 2048u;
    const float* xp0 = x + (size_t)(r0 + k - 3)*1024 + koff;
    const float* xp1 = x + (size_t)(r1 + k - 3)*1024 + koff;
    const float* wp0 = wkT + (size_t)k*393216 + (size_t)(n0+srow)*1024 + koff;
    const float* wp1 = wp0 + 64*1024;
    for (int k0=0;k0<1024;k0+=32){
      float4 a0a = make_float4(0,0,0,0), a0b = a0a, a1a = a0a, a1b = a0a;
      if (v0){ a0a = *(const float4*)(xp0+k0); a0b = *(const float4*)(xp0+k0+4); }
      if (v1){ a1a = *(const float4*)(xp1+k0); a1b = *(const float4*)(xp1+k0+4); }
      float4 b0a = *(const float4*)(wp0+k0), b0b = *(const float4*)(wp0+k0+4);
      float4 b1a = *(const float4*)(wp1+k0), b1b = *(const float4*)(wp1+k0+4);
      __syncthreads();
      h8_t hi, lo;
      split8(a0a,a0b,hi,lo); *(h8_t*)(AsH+tid*8)=hi;      *(h8_t*)(AsL+tid*8)=lo;
      split8(a1a,a1b,hi,lo); *(h8_t*)(AsH+2048+tid*8)=hi; *(h8_t*)(AsL+2048+tid*8)=lo;
      split8(b0a,b0b,hi,lo); *(h8_t*)(BsH+tid*8)=hi;      *(h8_t*)(BsL+tid*8)=lo;
      split8(b1a,b1b,hi,lo); *(h8_t*)(BsH+2048+tid*8)=hi; *(h8_t*)(BsL+2048+tid*8)=lo;
      __syncthreads();
      mma_block(AsH, AsL, BsH, BsL, aoff, boff, acc);
    }
  }
  #pragma unroll
  for (int m=0;m<4;m++){
    #pragma unroll
    for (int r=0;r<4;r++){
      const int row = m0 + wm + m*16 + kg*4 + r;
      #pragma unroll
      for (int n=0;n<4;n++){
        const int col = n0 + wn + n*16 + fr;
        C[(size_t)row*384 + col] = acc[m][n][r] + bias[col];
      }
    }
  }
}

// ---------------- LN (optionally fused depthwise conv k=7; optional split output) ----------------
template<bool CONV, bool SPLIT>
__global__ __launch_bounds__(384) void ln_kernel(
    const float* __restrict__ in,
    const float* __restrict__ dw, const float* __restrict__ db,
    const float* __restrict__ g, const float* __restrict__ b,
    float* __restrict__ out, _Float16* __restrict__ oh, _Float16* __restrict__ ol)
{
  __shared__ float rs[6], rs2[6], stat[2];
  const int m = blockIdx.x, d = threadIdx.x;
  float v;
  if (CONV){
    const int t = m & 2047;
    float a = db[d];
    #pragma unroll
    for (int k=0;k<7;k++){
      int tt = t + k - 3;
      if ((unsigned)tt < 2048u) a = fmaf(in[(size_t)(m + k - 3)*384 + d], dw[d*7 + k], a);
    }
    v = a;
  } else {
    v = in[(size_t)m*384 + d];
  }
  float s = v, s2 = v*v;
  #pragma unroll
  for (int o=1;o<64;o<<=1){ s += __shfl_xor(s,o); s2 += __shfl_xor(s2,o); }
  const int wid = d >> 6, lane = d & 63;
  if (lane == 0){ rs[wid]=s; rs2[wid]=s2; }
  __syncthreads();
  if (d == 0){
    float S=0.f, S2=0.f;
    #pragma unroll
    for (int w=0;w<6;w++){ S+=rs[w]; S2+=rs2[w]; }
    float mean = S*(1.0f/384.0f);
    float var = fmaxf(S2*(1.0f/384.0f) - mean*mean, 0.0f);
    stat[0]=mean; stat[1]=1.0f/sqrtf(var + 1e-6f);
  }
  __syncthreads();
  float o = (v - stat[0])*stat[1]*g[d] + b[d];
  if (SPLIT){
    _Float16 hh = (_Float16)o;
    oh[(size_t)m*384 + d] = hh;
    ol[(size_t)m*384 + d] = (_Float16)(o - (float)hh);
  } else {
    out[(size_t)m*384 + d] = o;
  }
}

// ---------------- VQ ----------------

__global__ __launch_bounds__(256) void vq_in_kernel(
    const float* __restrict__ enc, const float* __restrict__ wi,
    const float* __restrict__ bi, float* __restrict__ zn)
{
  __shared__ float sw[8192];
  const int tid = threadIdx.x;
  for (int i = tid*4; i < 8192; i += 1024) *(float4*)&sw[i] = *(const float4*)&wi[i];
  __syncthreads();
  const int wid = tid >> 6, lane = tid & 63;
  const size_t m = (size_t)blockIdx.x*4 + wid;
  float acc[8] = {};
  for (int j=0;j<16;j++){
    float v = enc[m*1024 + j*64 + lane];
    #pragma unroll
    for (int cd=0;cd<8;cd++) acc[cd] = fmaf(v, sw[cd*1024 + j*64 + lane], acc[cd]);
  }
  #pragma unroll
  for (int cd=0;cd<8;cd++)
    #pragma unroll
    for (int o=1;o<64;o<<=1) acc[cd] += __shfl_xor(acc[cd], o);
  if (lane == 0){
    float z[8], s = 0.f;
    #pragma unroll
    for (int cd=0;cd<8;cd++){ z[cd] = acc[cd] + bi[cd]; s += z[cd]*z[cd]; }
    float inv = 1.0f / fmaxf(sqrtf(s), 1e-12f);
    #pragma unroll
    for (int cd=0;cd<8;cd++) zn[m*8+cd] = z[cd]*inv;
  }
}

__global__ __launch_bounds__(256) void vq_argmax(
    const float* __restrict__ zn, const float* __restrict__ cbn,
    int* __restrict__ idx_out, float* __restrict__ idx_f)
{
  __shared__ float cbs[1024*8];
  const int tid = threadIdx.x;
  const size_t m = (size_t)blockIdx.x*256 + tid;
  float z[8];
  float4 z0 = *(const float4*)&zn[m*8];
  float4 z1 = *(const float4*)&zn[m*8+4];
  z[0]=z0.x; z[1]=z0.y; z[2]=z0.z; z[3]=z0.w; z[4]=z1.x; z[5]=z1.y; z[6]=z1.z; z[7]=z1.w;
  float best = -1e30f; int bidx = 0;
  for (int c0 = 0; c0 < 8192; c0 += 1024){
    __syncthreads();
    for (int i = tid*4; i < 8192; i += 1024) *(float4*)&cbs[i] = *(const float4*)&cbn[(size_t)c0*8 + i];
    __syncthreads();
    #pragma unroll 4
    for (int e = 0; e < 1024; ++e){
      const float4 ca = *(const float4*)&cbs[e*8];
      const float4 cb4 = *(const float4*)&cbs[e*8+4];
      float s = z[0]*ca.x + z[1]*ca.y + z[2]*ca.z + z[3]*ca.w
              + z[4]*cb4.x + z[5]*cb4.y + z[6]*cb4.z + z[7]*cb4.w;
      if (s > best){ best = s; bidx = c0 + e; }
    }
  }
  idx_out[m] = bidx;
  idx_f[m] = (float)bidx;
}

__global__ __launch_bounds__(256) void vq_out_kernel(
    const int* __restrict__ idx, const float* __restrict__ cb,
    const float* __restrict__ wo, const float* __restrict__ bo,
    float* __restrict__ outq)
{
  __shared__ float wT[8][1024];
  __shared__ float cbs[16][8];
  __shared__ int idxs[16];
  const int tid = threadIdx.x;
  #pragma unroll
  for (int j=0;j<4;j++){
    int hcol = j*256 + tid;
    float4 w0 = *(const float4*)&wo[(size_t)hcol*8];
    float4 w1 = *(const float4*)&wo[(size_t)hcol*8+4];
    wT[0][hcol]=w0.x; wT[1][hcol]=w0.y; wT[2][hcol]=w0.z; wT[3][hcol]=w0.w;
    wT[4][hcol]=w1.x; wT[5][hcol]=w1.y; wT[6][hcol]=w1.z; wT[7][hcol]=w1.w;
  }
  if (tid < 16) idxs[tid] = idx[blockIdx.x*16 + tid];
  __syncthreads();
  if (tid < 128){ int tk = tid>>3, cd = tid&7; cbs[tk][cd] = cb[(size_t)idxs[tk]*8 + cd]; }
  __syncthreads();
  float bb[4];
  #pragma unroll
  for (int j=0;j<4;j++) bb[j] = bo[j*256+tid];
  for (int tk=0;tk<16;tk++){
    const size_t m = (size_t)blockIdx.x*16 + tk;
    float c0=cbs[tk][0], c1=cbs[tk][1], c2=cbs[tk][2], c3=cbs[tk][3];
    float c4=cbs[tk][4], c5=cbs[tk][5], c6=cbs[tk][6], c7=cbs[tk][7];
    #pragma unroll
    for (int j=0;j<4;j++){
      int hcol = j*256 + tid;
      float v = bb[j];
      v = fmaf(c0, wT[0][hcol], v); v = fmaf(c1, wT[1][hcol], v);
      v = fmaf(c2, wT[2][hcol], v); v = fmaf(c3, wT[3][hcol], v);
      v = fmaf(c4, wT[4][hcol], v); v = fmaf(c5, wT[5][hcol], v);
      v = fmaf(c6, wT[6][hcol], v); v = fmaf(c7, wT[7][hcol], v);
      outq[m*1024 + hcol] = v;
    }
  }
}

// ---------------- host ----------------

extern "C" void kernel_launch(void* const* d_in, const int* in_sizes, int n_in,
                              void* d_out, int out_size, void* d_ws, size_t ws_size,
                              hipStream_t stream) {
  (void)in_sizes; (void)n_in; (void)out_size; (void)ws_size;
  const float* x   = (const float*)d_in[0];
  const float* eww = (const float*)d_in[1];
  const float* ewb = (const float*)d_in[2];
  const float* ng  = (const float*)d_in[3];
  const float* nb  = (const float*)d_in[4];
  const float* dww = (const float*)d_in[5];
  const float* dwb = (const float*)d_in[6];
  const float* lng = (const float*)d_in[7];
  const float* lnb = (const float*)d_in[8];
  const float* w1  = (const float*)d_in[9];
  const float* b1  = (const float*)d_in[10];
  const float* w2  = (const float*)d_in[11];
  const float* b2  = (const float*)d_in[12];
  const float* gma = (const float*)d_in[13];
  const float* fg  = (const float*)d_in[14];
  const float* fb  = (const float*)d_in[15];
  const float* ow  = (const float*)d_in[16];
  const float* ob  = (const float*)d_in[17];
  const float* viw = (const float*)d_in[18];
  const float* vib = (const float*)d_in[19];
  const float* cb  = (const float*)d_in[20];
  const float* vow = (const float*)d_in[21];
  const float* vob = (const float*)d_in[22];
  float* out = (float*)d_out;

  // workspace layout (floats), total ~118.3 MiB:
  // region A (16,777,216 f): wkT (embed) -> y1 splits (blocks) -> enc fp32 (VQ)
  // region C (6,291,456 f): h fp32 residual master
  // region D (6,291,456 f): embed-out fp32 -> LN-out splits
  // region E: zn, cbn, idx
  float* ws   = (float*)d_ws;
  float* regA = ws;
  float* wkT  = regA;
  _Float16* y1h = (_Float16*)regA;
  _Float16* y1l = (_Float16*)(regA + 8388608);
  float* enc  = regA;
  float* h    = ws + 16777216;
  float* yD   = ws + 23068672;
  float* yf32 = yD;
  _Float16* ylh = (_Float16*)yD;
  _Float16* yll = (_Float16*)(yD + 3145728);
  float* zn   = ws + 29360128;
  float* cbn  = zn + 131072;
  int*  idxb  = (int*)(cbn + 65536);

  prep_wk<<<dim3(1536), dim3(256), 0, stream>>>(eww, wkT);
  prep_cb<<<dim3(32),  dim3(256), 0, stream>>>(cb, cbn);

  // embed conv -> yf32 ; LN -> h (fp32)
  embed_f16<<<dim3(3,128), dim3(256), 0, stream>>>(x, wkT, ewb, yf32);
  ln_kernel<false,false><<<dim3(16384), dim3(384), 0, stream>>>(
      yf32, nullptr, nullptr, ng, nb, h, nullptr, nullptr);

  // 12 ConvNeXt blocks
  for (int i = 0; i < 12; ++i){
    ln_kernel<true,true><<<dim3(16384), dim3(384), 0, stream>>>(
        h, dww + (size_t)i*2688, dwb + (size_t)i*384,
        lng + (size_t)i*384, lnb + (size_t)i*384, nullptr, ylh, yll);
    for (int ic = 0; ic < 2; ++ic){
      // y1 = gelu(y @ w1_chunk^T + b1_chunk): M=16384, N=1024, K=384
      gemm_f16<1><<<dim3(8,128), dim3(256), 0, stream>>>(
          ylh, yll, 384,
          w1 + (size_t)i*786432 + (size_t)ic*393216, 384,
          b1 + (size_t)i*2048 + (size_t)ic*1024, nullptr,
          nullptr, y1h, y1l, 1024, 384);
      // h += gamma * (y1 @ w2_chunk^T + b2(once)): M=16384, N=384, K=1024
      gemm_f16<2><<<dim3(3,128), dim3(256), 0, stream>>>(
          y1h, y1l, 1024,
          w2 + (size_t)i*786432 + (size_t)ic*1024, 2048,
          (ic == 0) ? (b2 + (size_t)i*384) : nullptr,
          gma + (size_t)i*384,
          h, nullptr, nullptr, 384, 1024);
    }
  }

  // final LN -> splits ; enc = y @ ow^T + ob (fp32)
  ln_kernel<false,true><<<dim3(16384), dim3(384), 0, stream>>>(
      h, nullptr, nullptr, fg, fb, nullptr, ylh, yll);
  gemm_f16<0><<<dim3(8,128), dim3(256), 0, stream>>>(
      ylh, yll, 384, ow, 384, ob, nullptr, enc, nullptr, nullptr, 1024, 384);

  // VQ
  vq_in_kernel<<<dim3(4096), dim3(256), 0, stream>>>(enc, viw, vib, zn);
  vq_argmax<<<dim3(64), dim3(256), 0, stream>>>(zn, cbn, idxb, out);
  vq_out_kernel<<<dim3(1024), dim3(256), 0, stream>>>(idxb, cb, vow, vob, out + 16384);
}